// Round 8
// baseline (84.482 us; speedup 1.0000x reference)
//
#include <hip/hip_runtime.h>
#include <hip/hip_bf16.h>
#include <cstdint>

#define DT_F    0.01f
#define NB      16      // batch
#define T_SEQ   2048    // sequence
#define DD      1024    // d_in
#define NS      128     // n_state
#define CHUNK   64      // rows per chunk / scan length
#define NCH     32      // chunks per batch

using f32x4  = __attribute__((ext_vector_type(4))) float;
using bf16x8 = __attribute__((ext_vector_type(8))) short;
using fl4    = __attribute__((ext_vector_type(4))) float;

#define AS1(p) ((const __attribute__((address_space(1))) void*)(p))
#define AS3(p) ((__attribute__((address_space(3))) void*)(p))

__device__ __forceinline__ unsigned short f2bf(float f) {
  union { float f; unsigned u; } v; v.f = f;
  unsigned r = v.u + 0x7fffu + ((v.u >> 16) & 1u);   // RNE
  return (unsigned short)(r >> 16);
}
__device__ __forceinline__ float bf2f(unsigned short s) {
  union { unsigned u; float f; } v; v.u = ((unsigned)s) << 16;
  return v.f;
}
__device__ __forceinline__ unsigned short f2bf_hw(float f) {
  __hip_bfloat16 h = __float2bfloat16(f);
  return __builtin_bit_cast(unsigned short, h);
}

// a_disc from raw A (per n)
__device__ __forceinline__ void adisc(float Arn, float Ain, float& ar, float& ai) {
  const float dr = 1.f - 0.5f * DT_F * Arn;
  const float di = -0.5f * DT_F * Ain;
  const float inv = 1.f / (dr * dr + di * di);
  const float nr = 1.f + 0.5f * DT_F * Arn;
  const float nim = 0.5f * DT_F * Ain;
  ar = (nr * dr + nim * di) * inv;
  ai = (nim * dr - nr * di) * inv;
}

// ---------------------------------------------------------------------------
// prep_all: blocks 0..511 convert C->bf16; blocks 512..639 build B_disc rows.
// ---------------------------------------------------------------------------
__global__ void prep_all(const float* __restrict__ Ar, const float* __restrict__ Ai,
                         const float* __restrict__ B, const float* __restrict__ C,
                         unsigned short* __restrict__ W, unsigned short* __restrict__ Cb) {
  const int blk = blockIdx.x;
  const int tid = threadIdx.x;
  if (blk < 512) {
    const int i = blk * 256 + tid;
    Cb[i] = f2bf(C[i]);
    return;
  }
  const int n = blk - 512;
  const float ar = Ar[n], ai = Ai[n];
  const float dr = 1.f - 0.5f * DT_F * ar;
  const float di = -0.5f * DT_F * ai;
  const float inv = 1.f / (dr * dr + di * di);
  const float s  = sqrtf(DT_F);
  const float cr = s * dr * inv;
  const float ci = -s * di * inv;
  for (int d = tid; d < DD; d += 256) {
    const float b = B[(size_t)n * DD + d];
    W[(size_t)n * DD + d]        = f2bf(b * cr);
    W[(size_t)(NS + n) * DD + d] = f2bf(b * ci);
  }
}

// ---------------------------------------------------------------------------
// gemm1s (2-phase prefetch): per chunk blk, Bu_tile[64 x 256] = cvt(u) * W^T.
// Bs double-buffered (glds); As single-buffered, protected by raw s_barrier
// (all waves past MFMA issue -> LDS reads done) before the overwrite, so the
// B(t+1) glds stay in flight across it. One __syncthreads per K-step.
// Epilogue: acc -> swizzled LDS tile; 128-thread local scan; Re(h)->Hs, finals->F.
// ---------------------------------------------------------------------------
__global__ __launch_bounds__(256, 2) void gemm1s(const float* __restrict__ U,
                                                 const float* __restrict__ Ar,
                                                 const float* __restrict__ Ai,
                                                 const unsigned short* __restrict__ W,
                                                 unsigned short* __restrict__ Hs,
                                                 float* __restrict__ F) {
  __shared__ __align__(16) char smem[73728];                   // 72 KB
  unsigned short* As  = (unsigned short*)smem;                 // [64][64]   8 KB
  unsigned short* Bs0 = (unsigned short*)(smem + 8192);        // [256][64] 32 KB
  unsigned short* Bs1 = (unsigned short*)(smem + 8192 + 32768);
  char*           Bt  = smem;                                  // epilogue: 64 x 512 B swizzled

  const int tid  = threadIdx.x;
  const int lane = tid & 63;
  const int wave = tid >> 6;
  const int blk  = blockIdx.x;
  const size_t m0 = (size_t)blk * CHUNK;

  f32x4 acc[4][4];
  const f32x4 zero = {0.f, 0.f, 0.f, 0.f};
#pragma unroll
  for (int i = 0; i < 4; ++i)
#pragma unroll
    for (int j = 0; j < 4; ++j) acc[i][j] = zero;

  const int srow  = tid >> 2;           // 0..63
  const int scol  = (tid & 3) * 16;     // 0..48
  const int growl = lane >> 3;          // 0..7
  const int gcol  = (lane & 7) * 8;

  // ---- prologue: stage K-step 0 ----
  {
    const float* ga = U + (m0 + srow) * DD + scol;
    fl4 v0 = *(const fl4*)ga;
    fl4 v1 = *(const fl4*)(ga + 4);
    fl4 v2 = *(const fl4*)(ga + 8);
    fl4 v3 = *(const fl4*)(ga + 12);
#pragma unroll
    for (int g = 0; g < 8; ++g) {
      const int row = wave * 64 + g * 8;
      const unsigned short* gb = W + (size_t)(row + growl) * DD + gcol;
      __builtin_amdgcn_global_load_lds(AS1(gb), AS3(&Bs0[row * 64]), 16, 0, 0);
    }
    bf16x8 q0, q1;
#pragma unroll
    for (int e = 0; e < 4; ++e) {
      q0[e] = (short)f2bf_hw(v0[e]); q0[4 + e] = (short)f2bf_hw(v1[e]);
      q1[e] = (short)f2bf_hw(v2[e]); q1[4 + e] = (short)f2bf_hw(v3[e]);
    }
    *(bf16x8*)&As[srow * 64 + scol]     = q0;
    *(bf16x8*)&As[srow * 64 + scol + 8] = q1;
  }
  __syncthreads();

  // ---- main loop: prefetch t+1, compute t ----
  fl4 p0, p1, p2, p3;
  for (int t = 0; t < 16; ++t) {
    unsigned short* Bcur = (t & 1) ? Bs1 : Bs0;
    unsigned short* Bnxt = (t & 1) ? Bs0 : Bs1;
    if (t < 15) {
      const int k1 = (t + 1) * 64;
      const float* ga = U + (m0 + srow) * DD + k1 + scol;   // HBM: issue first
      p0 = *(const fl4*)ga;
      p1 = *(const fl4*)(ga + 4);
      p2 = *(const fl4*)(ga + 8);
      p3 = *(const fl4*)(ga + 12);
#pragma unroll
      for (int g = 0; g < 8; ++g) {                          // L2: glds next B
        const int row = wave * 64 + g * 8;
        const unsigned short* gb = W + (size_t)(row + growl) * DD + k1 + gcol;
        __builtin_amdgcn_global_load_lds(AS1(gb), AS3(&Bnxt[row * 64]), 16, 0, 0);
      }
    }
    // compute current tile (loads above stay in flight through the MFMAs)
#pragma unroll
    for (int ks = 0; ks < 2; ++ks) {
      bf16x8 af[4], bfr[4];
#pragma unroll
      for (int i = 0; i < 4; ++i)
        af[i] = *(const bf16x8*)&As[(i * 16 + (lane & 15)) * 64 + ks * 32 + (lane >> 4) * 8];
#pragma unroll
      for (int j = 0; j < 4; ++j)
        bfr[j] = *(const bf16x8*)&Bcur[(wave * 64 + j * 16 + (lane & 15)) * 64 + ks * 32 + (lane >> 4) * 8];
#pragma unroll
      for (int i = 0; i < 4; ++i)
#pragma unroll
        for (int j = 0; j < 4; ++j)
          acc[i][j] = __builtin_amdgcn_mfma_f32_16x16x32_bf16(af[i], bfr[j], acc[i][j], 0, 0, 0);
    }
    if (t < 15) {
      // all waves past MFMA issue -> As LDS reads complete; glds NOT drained
      __builtin_amdgcn_s_barrier();
      __builtin_amdgcn_sched_barrier(0);
      bf16x8 q0, q1;
#pragma unroll
      for (int e = 0; e < 4; ++e) {
        q0[e] = (short)f2bf_hw(p0[e]); q0[4 + e] = (short)f2bf_hw(p1[e]);
        q1[e] = (short)f2bf_hw(p2[e]); q1[4 + e] = (short)f2bf_hw(p3[e]);
      }
      *(bf16x8*)&As[srow * 64 + scol]     = q0;
      *(bf16x8*)&As[srow * 64 + scol + 8] = q1;
      __syncthreads();   // drains glds(Bnxt) + As writes
    }
  }
  __syncthreads();   // last MFMA's LDS reads done before Bt overwrite

  // epilogue: acc -> swizzled Bt. byte(t, cc) = t*512 + ((cc*2) ^ ((t&7)<<4))
#pragma unroll
  for (int i = 0; i < 4; ++i) {
#pragma unroll
    for (int j = 0; j < 4; ++j) {
      const int cc = wave * 64 + j * 16 + (lane & 15);
#pragma unroll
      for (int q = 0; q < 4; ++q) {
        const int t = i * 16 + (lane >> 4) * 4 + q;
        *(unsigned short*)(Bt + t * 512 + ((cc * 2) ^ ((t & 7) << 4))) = f2bf_hw(acc[i][j][q]);
      }
    }
  }
  __syncthreads();

  // local scan (threads 0..127, one per n); Re(h) bf16 -> Hs; finals -> F
  if (tid < 128) {
    const int n = tid;
    float ar, ai; adisc(Ar[n], Ai[n], ar, ai);
    float hr = 0.f, hi = 0.f;
    unsigned short* o = Hs + (size_t)blk * (CHUNK * NS) + n;
#pragma unroll 8
    for (int t = 0; t < CHUNK; ++t) {
      const int reByte = t * 512 + ((n * 2) ^ ((t & 7) << 4));
      const float br = bf2f(*(const unsigned short*)(Bt + reByte));
      const float bi = bf2f(*(const unsigned short*)(Bt + reByte + 256));
      const float xr = fmaf(ar, hr, fmaf(-ai, hi, br));
      const float xi = fmaf(ar, hi, fmaf(ai, hr, bi));
      hr = xr; hi = xi;
      o[t * NS] = f2bf(hr);
    }
    F[(size_t)blk * 256 + n]       = hr;
    F[(size_t)blk * 256 + 128 + n] = hi;
  }
}

// ---------------------------------------------------------------------------
// gemm2s (unchanged from R7): glds-load Hs tile with inverse-swizzled source;
// carry fold + in-LDS correction; GEMM2 y[64 x 1024] = Hl * Cb^T.
// ---------------------------------------------------------------------------
__global__ __launch_bounds__(256, 2) void gemm2s(const unsigned short* __restrict__ Hs,
                                                 const float* __restrict__ F,
                                                 const float* __restrict__ Ar,
                                                 const float* __restrict__ Ai,
                                                 const unsigned short* __restrict__ Cb,
                                                 float* __restrict__ y) {
  __shared__ __align__(16) char Hl[64 * 256];   // 16 KB swizzled Re(h)
  const int tid  = threadIdx.x;
  const int lane = tid & 63;
  const int wave = tid >> 6;
  const int blk  = blockIdx.x;
  const int c    = blk & 31;
  const size_t m0 = (size_t)blk * CHUNK;

  const char* tile = (const char*)Hs + (size_t)blk * (CHUNK * NS * 2);
#pragma unroll
  for (int g = 0; g < 4; ++g) {
    const int r0 = wave * 16 + g * 4;
    const int r  = r0 + (lane >> 4);
    const int srcOff = r * 256 + ((((lane & 15)) * 16) ^ ((r & 7) << 4));
    __builtin_amdgcn_global_load_lds(AS1(tile + srcOff), AS3(Hl + r0 * 256), 16, 0, 0);
  }
  __syncthreads();

  if (tid < 128) {
    const int n = tid;
    float ar, ai; adisc(Ar[n], Ai[n], ar, ai);
    if (c != 0) {
      float alr = ar, ali = ai;                 // a^CHUNK (2^6)
#pragma unroll
      for (int s = 0; s < 6; ++s) {
        const float tr = alr * alr - ali * ali;
        const float ti = 2.f * alr * ali;
        alr = tr; ali = ti;
      }
      float cr = 0.f, ci = 0.f;
      const float* Fb = F + (size_t)(blk - c) * 256;
      for (int cc = 0; cc < c; ++cc) {
        const float fr = Fb[(size_t)cc * 256 + n];
        const float fi = Fb[(size_t)cc * 256 + 128 + n];
        const float xr = fmaf(alr, cr, fmaf(-ali, ci, fr));
        const float xi = fmaf(alr, ci, fmaf(ali, cr, fi));
        cr = xr; ci = xi;
      }
      float gr = ar * cr - ai * ci;             // g_t = a^{t+1} * carry
      float gi = ar * ci + ai * cr;
#pragma unroll 8
      for (int t = 0; t < CHUNK; ++t) {
        unsigned short* pp = (unsigned short*)(Hl + t * 256 + ((n * 2) ^ ((t & 7) << 4)));
        *pp = f2bf(bf2f(*pp) + gr);
        const float xr = ar * gr - ai * gi;
        const float xi = ar * gi + ai * gr;
        gr = xr; gi = xi;
      }
    }
  }
  __syncthreads();

  const f32x4 zero = {0.f, 0.f, 0.f, 0.f};
#pragma unroll
  for (int cg = 0; cg < 4; ++cg) {
    const int d0 = wave * 256 + cg * 64;
    f32x4 oacc[4][4];
#pragma unroll
    for (int i = 0; i < 4; ++i)
#pragma unroll
      for (int j = 0; j < 4; ++j) oacc[i][j] = zero;

#pragma unroll
    for (int ks = 0; ks < 4; ++ks) {
      bf16x8 af[4], bfr[4];
#pragma unroll
      for (int i = 0; i < 4; ++i) {
        const int r = i * 16 + (lane & 15);
        af[i] = *(const bf16x8*)(Hl + r * 256 + ((ks * 64 + (lane >> 4) * 16) ^ ((r & 7) << 4)));
      }
#pragma unroll
      for (int j = 0; j < 4; ++j)
        bfr[j] = *(const bf16x8*)(Cb + (size_t)(d0 + j * 16 + (lane & 15)) * NS + ks * 32 + (lane >> 4) * 8);
#pragma unroll
      for (int i = 0; i < 4; ++i)
#pragma unroll
        for (int j = 0; j < 4; ++j)
          oacc[i][j] = __builtin_amdgcn_mfma_f32_16x16x32_bf16(af[i], bfr[j], oacc[i][j], 0, 0, 0);
    }
#pragma unroll
    for (int i = 0; i < 4; ++i) {
      const size_t r0 = m0 + i * 16 + (lane >> 4) * 4;
#pragma unroll
      for (int j = 0; j < 4; ++j) {
        const int d = d0 + j * 16 + (lane & 15);
#pragma unroll
        for (int q = 0; q < 4; ++q)
          y[(r0 + q) * DD + d] = oacc[i][j][q];
      }
    }
  }
}

// ---------------------------------------------------------------------------
extern "C" void kernel_launch(void* const* d_in, const int* in_sizes, int n_in,
                              void* d_out, int out_size, void* d_ws, size_t ws_size,
                              hipStream_t stream) {
  const float* u  = (const float*)d_in[0];
  const float* Ar = (const float*)d_in[1];
  const float* Ai = (const float*)d_in[2];
  const float* B  = (const float*)d_in[3];
  const float* C  = (const float*)d_in[4];
  float* y = (float*)d_out;
  char* ws = (char*)d_ws;

  unsigned short* W  = (unsigned short*)(ws);                  // 512 KB (B_disc bf16)
  unsigned short* Cb = (unsigned short*)(ws + (512 << 10));    // 256 KB (C bf16)
  float*          F  = (float*)(ws + (768 << 10));             // 512 KB (chunk finals f32)
  unsigned short* Hs = (unsigned short*)(ws + (1280 << 10));   // 8 MB   (Re(h_local) bf16)

  prep_all<<<dim3(640), dim3(256), 0, stream>>>(Ar, Ai, B, C, W, Cb);
  gemm1s<<<dim3(NB * NCH), dim3(256), 0, stream>>>(u, Ar, Ai, W, Hs, F);
  gemm2s<<<dim3(NB * NCH), dim3(256), 0, stream>>>(Hs, F, Ar, Ai, Cb, y);
}